// Round 1
// baseline (2653.767 us; speedup 1.0000x reference)
//
#include <hip/hip_runtime.h>
#include <math.h>

#define N_USERS 100000
#define N_ITEMS 100000
#define EMB 64
#define N_NODES (N_USERS + N_ITEMS + 2)   // 200002
#define N_EDGES 1200000
#define ND ((long)N_NODES * EMB)          // 12,800,128

// Build total = concat(user_emb, item_emb)
__global__ void concat_kernel(const float* __restrict__ u,
                              const float* __restrict__ it,
                              float* __restrict__ t) {
    long i = (long)blockIdx.x * blockDim.x + threadIdx.x;
    if (i >= ND) return;
    long n = i >> 6;  // node index
    if (n < (long)(N_USERS + 1)) {
        t[i] = u[i];
    } else {
        t[i] = it[i - (long)(N_USERS + 1) * EMB];
    }
}

// y[r] += x[c] * w  for each edge (push-scatter, one wave per edge, lane = dim)
__global__ void spmm_kernel(const int* __restrict__ rows,
                            const int* __restrict__ cols,
                            const float* __restrict__ w,
                            const float* __restrict__ x,
                            float* __restrict__ y) {
    long tid = (long)blockIdx.x * blockDim.x + threadIdx.x;
    int e = (int)(tid >> 6);
    if (e >= N_EDGES) return;
    int d = (int)(tid & 63);
    int r = rows[e];
    int c = cols[e];
    float val = x[(long)c * EMB + d] * w[e];
    atomicAdd(&y[(long)r * EMB + d], val);
}

// C = T + A + B (elementwise)
__global__ void acc_kernel(const float* __restrict__ T,
                           const float* __restrict__ A,
                           const float* __restrict__ Bb,
                           float* __restrict__ C) {
    long i = (long)blockIdx.x * blockDim.x + threadIdx.x;
    if (i >= ND) return;
    C[i] = T[i] + A[i] + Bb[i];
}

// O = l2_normalize((C + A) / 4) + T      (one wave per node, lane = dim)
__global__ void final_kernel(const float* __restrict__ C,
                             const float* __restrict__ A,
                             const float* __restrict__ T,
                             float* __restrict__ O) {
    int wave = threadIdx.x >> 6;
    long n = (long)blockIdx.x * 4 + wave;
    if (n >= (long)N_NODES) return;
    int d = threadIdx.x & 63;
    long i = n * (long)EMB + d;
    float v = (C[i] + A[i]) * 0.25f;
    float ss = v * v;
    #pragma unroll
    for (int off = 32; off > 0; off >>= 1) {
        ss += __shfl_xor(ss, off, 64);
    }
    float nm = sqrtf(ss);
    O[i] = v / fmaxf(nm, 1e-12f) + T[i];
}

extern "C" void kernel_launch(void* const* d_in, const int* in_sizes, int n_in,
                              void* d_out, int out_size, void* d_ws, size_t ws_size,
                              hipStream_t stream) {
    const float* user_emb = (const float*)d_in[0];
    const float* item_emb = (const float*)d_in[1];
    const int*   rows     = (const int*)d_in[2];
    const int*   cols     = (const int*)d_in[3];
    const float* weights  = (const float*)d_in[4];
    float* out = (float*)d_out;

    float* A = (float*)d_ws;           // ND floats
    float* B = A + ND;                 // ND floats
    const size_t buf_bytes = (size_t)ND * sizeof(float);

    // Initial total lives in out[2] (scratch until behavior 2 writes it)
    float* T0 = out + 2 * ND;

    const int TPB = 256;
    const long nd_blocks = (ND + TPB - 1) / TPB;
    const long spmm_blocks = ((long)N_EDGES * 64 + TPB - 1) / TPB;
    const long node_blocks = (N_NODES + 3) / 4;  // 4 waves/block in final_kernel

    concat_kernel<<<nd_blocks, TPB, 0, stream>>>(user_emb, item_emb, T0);

    for (int b = 0; b < 3; ++b) {
        const int*   rb = rows    + (long)b * N_EDGES;
        const int*   cb = cols    + (long)b * N_EDGES;
        const float* wb = weights + (long)b * N_EDGES;
        const float* Tin = (b == 0) ? T0 : (out + (long)(b - 1) * ND);
        float* C = out + (long)b * ND;   // acc buffer aliases out[b]

        // y1 = A @ Tin
        hipMemsetAsync(A, 0, buf_bytes, stream);
        spmm_kernel<<<spmm_blocks, TPB, 0, stream>>>(rb, cb, wb, Tin, A);
        // y2 = A @ y1
        hipMemsetAsync(B, 0, buf_bytes, stream);
        spmm_kernel<<<spmm_blocks, TPB, 0, stream>>>(rb, cb, wb, A, B);
        // C = Tin + y1 + y2
        acc_kernel<<<nd_blocks, TPB, 0, stream>>>(Tin, A, B, C);
        // y3 = A @ y2  (reuse A; y1 already consumed)
        hipMemsetAsync(A, 0, buf_bytes, stream);
        spmm_kernel<<<spmm_blocks, TPB, 0, stream>>>(rb, cb, wb, B, A);
        // out[b] = l2_normalize((C + y3)/4) + Tin   (in-place on C)
        final_kernel<<<node_blocks, TPB, 0, stream>>>(C, A, Tin, C);
    }
}

// Round 2
// 1803.603 us; speedup vs baseline: 1.4714x; 1.4714x over previous
//
#include <hip/hip_runtime.h>
#include <math.h>

#define N_USERS 100000
#define N_ITEMS 100000
#define EMB 64
#define N_NODES (N_USERS + N_ITEMS + 2)   // 200002
#define N_EDGES 1200000
#define ND ((long)N_NODES * (long)EMB)    // 12,800,128
#define NB_SCAN ((N_NODES + 255) / 256)   // 782

// Build total = concat(user_emb, item_emb), vectorized float4
__global__ void concat_kernel(const float4* __restrict__ u,
                              const float4* __restrict__ it,
                              float4* __restrict__ t) {
    long i = (long)blockIdx.x * blockDim.x + threadIdx.x;  // over ND/4
    if (i >= ND / 4) return;
    long n = i >> 4;  // 16 float4 per 64-float row
    if (n < (long)(N_USERS + 1)) t[i] = u[i];
    else                         t[i] = it[i - (long)(N_USERS + 1) * 16];
}

// counting-sort step 1: per-row degree histogram
__global__ void hist_kernel(const int* __restrict__ rows, int* __restrict__ cnt) {
    int e = blockIdx.x * blockDim.x + threadIdx.x;
    if (e < N_EDGES) atomicAdd(&cnt[rows[e]], 1);
}

// scan step 1: per-block exclusive scan + block totals
__global__ void scan1_kernel(const int* __restrict__ cnt, int* __restrict__ excl,
                             int* __restrict__ partials) {
    __shared__ int sm[256];
    int tid = threadIdx.x;
    int i = blockIdx.x * 256 + tid;
    int v = (i < N_NODES) ? cnt[i] : 0;
    sm[tid] = v;
    __syncthreads();
    for (int off = 1; off < 256; off <<= 1) {
        int t = (tid >= off) ? sm[tid - off] : 0;
        __syncthreads();
        sm[tid] += t;
        __syncthreads();
    }
    if (i < N_NODES) excl[i] = sm[tid] - v;
    if (tid == 255) partials[blockIdx.x] = sm[255];
}

// scan step 2: single-block scan of the 782 block totals
__global__ void scan2_kernel(int* __restrict__ partials) {
    __shared__ int sm[1024];
    int tid = threadIdx.x;
    int v = (tid < NB_SCAN) ? partials[tid] : 0;
    sm[tid] = v;
    __syncthreads();
    for (int off = 1; off < 1024; off <<= 1) {
        int t = (tid >= off) ? sm[tid - off] : 0;
        __syncthreads();
        sm[tid] += t;
        __syncthreads();
    }
    if (tid < NB_SCAN) partials[tid] = sm[tid] - v;  // exclusive across blocks
}

// scan step 3: finalize row_ptr and init scatter cursors
__global__ void scan3_kernel(const int* __restrict__ excl, const int* __restrict__ partials,
                             int* __restrict__ rowptr, int* __restrict__ cursor) {
    int i = blockIdx.x * 256 + threadIdx.x;
    if (i < N_NODES) {
        int v = excl[i] + partials[blockIdx.x];
        rowptr[i] = v;
        cursor[i] = v;
    }
    if (i == 0) rowptr[N_NODES] = N_EDGES;
}

// counting-sort step 2: place (col, w) into row-sorted arrays
__global__ void scatter_kernel(const int* __restrict__ rows, const int* __restrict__ cols,
                               const float* __restrict__ w, int* __restrict__ cursor,
                               int* __restrict__ scol, float* __restrict__ sw) {
    int e = blockIdx.x * blockDim.x + threadIdx.x;
    if (e >= N_EDGES) return;
    int r = rows[e];
    int p = atomicAdd(&cursor[r], 1);
    scol[p] = cols[e];
    sw[p] = w[e];
}

// CSR SpMM: one 64-lane wave per row, lane = dim. No atomics, coalesced write.
__global__ void spmm_csr_kernel(const int* __restrict__ rowptr, const int* __restrict__ scol,
                                const float* __restrict__ sw, const float* __restrict__ x,
                                float* __restrict__ y) {
    int n = blockIdx.x * 4 + (threadIdx.x >> 6);
    if (n >= N_NODES) return;
    int d = threadIdx.x & 63;
    int s = rowptr[n], e = rowptr[n + 1];
    float acc = 0.f;
    for (int i = s; i < e; ++i) {
        int c = scol[i];
        float wt = sw[i];
        acc = fmaf(x[(long)c * EMB + d], wt, acc);
    }
    __builtin_nontemporal_store(acc, &y[(long)n * EMB + d]);
}

// S = Tin + y1(in A) + y2, in-place into A
__global__ void sum_kernel(const float* __restrict__ Tin, const float* __restrict__ y2,
                           float* __restrict__ A) {
    long i = (long)blockIdx.x * blockDim.x + threadIdx.x;
    if (i >= ND) return;
    A[i] = Tin[i] + A[i] + y2[i];
}

// Fused layer 3: y3 = spmm(y2); v = (S + y3)/4; out = v / max(||v||,eps) + Tin
// NOTE: for b=2 `out` aliases S (A buffer) — safe: S only read at own row before write.
__global__ void spmm_csr_final_kernel(const int* __restrict__ rowptr, const int* __restrict__ scol,
                                      const float* __restrict__ sw, const float* __restrict__ x,
                                      const float* S, const float* __restrict__ Tin,
                                      float* out) {
    int n = blockIdx.x * 4 + (threadIdx.x >> 6);
    if (n >= N_NODES) return;
    int d = threadIdx.x & 63;
    long i = (long)n * EMB + d;
    int s = rowptr[n], e = rowptr[n + 1];
    float acc = 0.f;
    for (int k = s; k < e; ++k) {
        int c = scol[k];
        float wt = sw[k];
        acc = fmaf(x[(long)c * EMB + d], wt, acc);
    }
    float v = (S[i] + acc) * 0.25f;
    float ss = v * v;
    #pragma unroll
    for (int off = 32; off > 0; off >>= 1) ss += __shfl_xor(ss, off, 64);
    float nm = sqrtf(ss);
    __builtin_nontemporal_store(v / fmaxf(nm, 1e-12f) + Tin[i], &out[i]);
}

extern "C" void kernel_launch(void* const* d_in, const int* in_sizes, int n_in,
                              void* d_out, int out_size, void* d_ws, size_t ws_size,
                              hipStream_t stream) {
    const float* user_emb = (const float*)d_in[0];
    const float* item_emb = (const float*)d_in[1];
    const int*   rows     = (const int*)d_in[2];
    const int*   cols     = (const int*)d_in[3];
    const float* weights  = (const float*)d_in[4];
    float* out = (float*)d_out;

    // Workspace carve-up (~65 MB)
    float* A       = (float*)d_ws;            // ND floats: y1, then S, then (b=2) final staging
    int*   scol    = (int*)(A + ND);          // N_EDGES
    float* sw      = (float*)(scol + N_EDGES);// N_EDGES
    int*   rowptr  = (int*)(sw + N_EDGES);    // N_NODES+1 (+1 pad)
    int*   cursor  = rowptr + N_NODES + 2;    // N_NODES
    int*   cnt     = cursor + N_NODES;        // N_NODES
    int*   excl    = cnt + N_NODES;           // N_NODES
    int*   partials= excl + N_NODES;          // 1024

    float* T0 = out + 2 * ND;  // initial total lives in out[2] until b=0 consumes it

    const int TPB = 256;
    const long v4_blocks   = (ND / 4 + TPB - 1) / TPB;
    const long edge_blocks = (N_EDGES + TPB - 1) / TPB;
    const long node_blocks = ((long)N_NODES + 3) / 4;   // 4 waves/block
    const long nd_blocks   = (ND + TPB - 1) / TPB;

    concat_kernel<<<v4_blocks, TPB, 0, stream>>>((const float4*)user_emb,
                                                 (const float4*)item_emb, (float4*)T0);

    for (int b = 0; b < 3; ++b) {
        const int*   rb = rows    + (long)b * N_EDGES;
        const int*   cb = cols    + (long)b * N_EDGES;
        const float* wb = weights + (long)b * N_EDGES;
        const float* Tin = (b == 0) ? T0 : (out + (long)(b - 1) * ND);
        float* Bsl = (b == 0) ? (out + ND) : (out + 2 * ND);  // free out slice for y2
        float* Dst = (b == 2) ? A : (out + (long)b * ND);     // b=2 stages via A

        // --- build CSR (row-sorted edge copy), reused by all 3 layers ---
        hipMemsetAsync(cnt, 0, (size_t)N_NODES * sizeof(int), stream);
        hist_kernel<<<edge_blocks, TPB, 0, stream>>>(rb, cnt);
        scan1_kernel<<<NB_SCAN, 256, 0, stream>>>(cnt, excl, partials);
        scan2_kernel<<<1, 1024, 0, stream>>>(partials);
        scan3_kernel<<<NB_SCAN, 256, 0, stream>>>(excl, partials, rowptr, cursor);
        scatter_kernel<<<edge_blocks, TPB, 0, stream>>>(rb, cb, wb, cursor, scol, sw);

        // --- 3 LightGCN layers ---
        spmm_csr_kernel<<<node_blocks, TPB, 0, stream>>>(rowptr, scol, sw, Tin, A);   // y1
        spmm_csr_kernel<<<node_blocks, TPB, 0, stream>>>(rowptr, scol, sw, A, Bsl);   // y2
        sum_kernel<<<nd_blocks, TPB, 0, stream>>>(Tin, Bsl, A);                       // S=Tin+y1+y2
        spmm_csr_final_kernel<<<node_blocks, TPB, 0, stream>>>(rowptr, scol, sw, Bsl,
                                                               A, Tin, Dst);
        if (b == 2) {
            hipMemcpyAsync(out + 2 * ND, A, (size_t)ND * sizeof(float),
                           hipMemcpyDeviceToDevice, stream);
        }
    }
}

// Round 3
// 946.072 us; speedup vs baseline: 2.8050x; 1.9064x over previous
//
#include <hip/hip_runtime.h>
#include <math.h>

#define N_USERS 100000
#define N_ITEMS 100000
#define EMB 64
#define N_NODES (N_USERS + N_ITEMS + 2)   // 200002
#define N_EDGES 1200000
#define ND ((long)N_NODES * (long)EMB)    // 12,800,128
#define NB_SCAN ((N_NODES + 255) / 256)   // 782

// Build total = concat(user_emb, item_emb), vectorized float4
__global__ void concat_kernel(const float4* __restrict__ u,
                              const float4* __restrict__ it,
                              float4* __restrict__ t) {
    long i = (long)blockIdx.x * blockDim.x + threadIdx.x;  // over ND/4
    if (i >= ND / 4) return;
    long n = i >> 4;  // 16 float4 per 64-float row
    if (n < (long)(N_USERS + 1)) t[i] = u[i];
    else                         t[i] = it[i - (long)(N_USERS + 1) * 16];
}

// counting-sort step 1: per-row degree histogram
__global__ void hist_kernel(const int* __restrict__ rows, int* __restrict__ cnt) {
    int e = blockIdx.x * blockDim.x + threadIdx.x;
    if (e < N_EDGES) atomicAdd(&cnt[rows[e]], 1);
}

// scan step 1: per-block exclusive scan + block totals
__global__ void scan1_kernel(const int* __restrict__ cnt, int* __restrict__ excl,
                             int* __restrict__ partials) {
    __shared__ int sm[256];
    int tid = threadIdx.x;
    int i = blockIdx.x * 256 + tid;
    int v = (i < N_NODES) ? cnt[i] : 0;
    sm[tid] = v;
    __syncthreads();
    for (int off = 1; off < 256; off <<= 1) {
        int t = (tid >= off) ? sm[tid - off] : 0;
        __syncthreads();
        sm[tid] += t;
        __syncthreads();
    }
    if (i < N_NODES) excl[i] = sm[tid] - v;
    if (tid == 255) partials[blockIdx.x] = sm[255];
}

// scan step 2: single-block scan of the 782 block totals
__global__ void scan2_kernel(int* __restrict__ partials) {
    __shared__ int sm[1024];
    int tid = threadIdx.x;
    int v = (tid < NB_SCAN) ? partials[tid] : 0;
    sm[tid] = v;
    __syncthreads();
    for (int off = 1; off < 1024; off <<= 1) {
        int t = (tid >= off) ? sm[tid - off] : 0;
        __syncthreads();
        sm[tid] += t;
        __syncthreads();
    }
    if (tid < NB_SCAN) partials[tid] = sm[tid] - v;  // exclusive across blocks
}

// scan step 3: finalize row_ptr and init scatter cursors
__global__ void scan3_kernel(const int* __restrict__ excl, const int* __restrict__ partials,
                             int* __restrict__ rowptr, int* __restrict__ cursor) {
    int i = blockIdx.x * 256 + threadIdx.x;
    if (i < N_NODES) {
        int v = excl[i] + partials[blockIdx.x];
        rowptr[i] = v;
        cursor[i] = v;
    }
    if (i == 0) rowptr[N_NODES] = N_EDGES;
}

// counting-sort step 2: place packed (col, w) into row-sorted array
__global__ void scatter_kernel(const int* __restrict__ rows, const int* __restrict__ cols,
                               const float* __restrict__ w, int* __restrict__ cursor,
                               int2* __restrict__ sedge) {
    int e = blockIdx.x * blockDim.x + threadIdx.x;
    if (e >= N_EDGES) return;
    int r = rows[e];
    int p = atomicAdd(&cursor[r], 1);
    int2 pk;
    pk.x = cols[e];
    pk.y = __float_as_int(w[e]);
    sedge[p] = pk;
}

// CSR SpMM: 16 lanes (float4 each) per row, 4 rows per wave -> 4 independent
// gather streams; inner loop unrolled x2 -> up to 8 outstanding gathers/wave.
__global__ void spmm_csr_kernel(const int* __restrict__ rowptr,
                                const int2* __restrict__ sedge,
                                const float4* __restrict__ x,
                                float4* __restrict__ y) {
    int wid  = threadIdx.x >> 6;
    int lane = threadIdx.x & 63;
    int r = lane >> 4;          // sub-row 0..3
    int q = lane & 15;          // float4 slot within the 64-dim row
    int n = (blockIdx.x * 4 + wid) * 4 + r;
    if (n >= N_NODES) return;
    int s = rowptr[n], e = rowptr[n + 1];
    float4 acc = make_float4(0.f, 0.f, 0.f, 0.f);
    int i = s;
    for (; i + 2 <= e; i += 2) {
        int2 e0 = sedge[i];
        int2 e1 = sedge[i + 1];
        float4 v0 = x[(long)e0.x * 16 + q];
        float4 v1 = x[(long)e1.x * 16 + q];
        float w0 = __int_as_float(e0.y);
        float w1 = __int_as_float(e1.y);
        acc.x = fmaf(w0, v0.x, acc.x); acc.y = fmaf(w0, v0.y, acc.y);
        acc.z = fmaf(w0, v0.z, acc.z); acc.w = fmaf(w0, v0.w, acc.w);
        acc.x = fmaf(w1, v1.x, acc.x); acc.y = fmaf(w1, v1.y, acc.y);
        acc.z = fmaf(w1, v1.z, acc.z); acc.w = fmaf(w1, v1.w, acc.w);
    }
    if (i < e) {
        int2 e0 = sedge[i];
        float4 v0 = x[(long)e0.x * 16 + q];
        float w0 = __int_as_float(e0.y);
        acc.x = fmaf(w0, v0.x, acc.x); acc.y = fmaf(w0, v0.y, acc.y);
        acc.z = fmaf(w0, v0.z, acc.z); acc.w = fmaf(w0, v0.w, acc.w);
    }
    y[(long)n * 16 + q] = acc;
}

// Fused layer 3 + epilogue: y3 = spmm(y2); v = (Tin + y1 + y2 + y3)/4;
// out = v / max(||v||, eps) + Tin.  Own-row reads of Tin/P/Q; gather from Q.
// `out` may alias P or Tin (own-row read-then-write, same thread) but NOT Q.
__global__ void spmm_final_kernel(const int* __restrict__ rowptr,
                                  const int2* __restrict__ sedge,
                                  const float4* __restrict__ x,   // = Q (y2)
                                  const float4* __restrict__ Tin,
                                  const float4* P,                 // y1
                                  const float4* __restrict__ Q,    // y2
                                  float4* out) {
    int wid  = threadIdx.x >> 6;
    int lane = threadIdx.x & 63;
    int r = lane >> 4;
    int q = lane & 15;
    int n = (blockIdx.x * 4 + wid) * 4 + r;
    if (n >= N_NODES) return;
    int s = rowptr[n], e = rowptr[n + 1];
    float4 acc = make_float4(0.f, 0.f, 0.f, 0.f);
    int i = s;
    for (; i + 2 <= e; i += 2) {
        int2 e0 = sedge[i];
        int2 e1 = sedge[i + 1];
        float4 v0 = x[(long)e0.x * 16 + q];
        float4 v1 = x[(long)e1.x * 16 + q];
        float w0 = __int_as_float(e0.y);
        float w1 = __int_as_float(e1.y);
        acc.x = fmaf(w0, v0.x, acc.x); acc.y = fmaf(w0, v0.y, acc.y);
        acc.z = fmaf(w0, v0.z, acc.z); acc.w = fmaf(w0, v0.w, acc.w);
        acc.x = fmaf(w1, v1.x, acc.x); acc.y = fmaf(w1, v1.y, acc.y);
        acc.z = fmaf(w1, v1.z, acc.z); acc.w = fmaf(w1, v1.w, acc.w);
    }
    if (i < e) {
        int2 e0 = sedge[i];
        float4 v0 = x[(long)e0.x * 16 + q];
        float w0 = __int_as_float(e0.y);
        acc.x = fmaf(w0, v0.x, acc.x); acc.y = fmaf(w0, v0.y, acc.y);
        acc.z = fmaf(w0, v0.z, acc.z); acc.w = fmaf(w0, v0.w, acc.w);
    }
    long o = (long)n * 16 + q;
    float4 t = Tin[o];
    float4 p = P[o];
    float4 qq = Q[o];
    float4 v;
    v.x = (t.x + p.x + qq.x + acc.x) * 0.25f;
    v.y = (t.y + p.y + qq.y + acc.y) * 0.25f;
    v.z = (t.z + p.z + qq.z + acc.z) * 0.25f;
    v.w = (t.w + p.w + qq.w + acc.w) * 0.25f;
    float ss = v.x * v.x + v.y * v.y + v.z * v.z + v.w * v.w;
    #pragma unroll
    for (int off = 1; off < 16; off <<= 1) ss += __shfl_xor(ss, off, 64);
    float inv = 1.0f / fmaxf(sqrtf(ss), 1e-12f);
    float4 ov;
    ov.x = v.x * inv + t.x;
    ov.y = v.y * inv + t.y;
    ov.z = v.z * inv + t.z;
    ov.w = v.w * inv + t.w;
    out[o] = ov;
}

extern "C" void kernel_launch(void* const* d_in, const int* in_sizes, int n_in,
                              void* d_out, int out_size, void* d_ws, size_t ws_size,
                              hipStream_t stream) {
    const float* user_emb = (const float*)d_in[0];
    const float* item_emb = (const float*)d_in[1];
    const int*   rows     = (const int*)d_in[2];
    const int*   cols     = (const int*)d_in[3];
    const float* weights  = (const float*)d_in[4];
    float* out = (float*)d_out;

    // Workspace carve-up (~65 MB)
    float* A        = (float*)d_ws;             // ND floats
    int2*  sedge    = (int2*)(A + ND);          // N_EDGES packed (col,w)
    int*   rowptr   = (int*)(sedge + N_EDGES);  // N_NODES+1 (+pad)
    int*   cursor   = rowptr + N_NODES + 2;     // N_NODES
    int*   cnt      = cursor + N_NODES;         // N_NODES
    int*   excl     = cnt + N_NODES;            // N_NODES
    int*   partials = excl + N_NODES;           // 1024

    float* o0 = out;
    float* o1 = out + ND;
    float* o2 = out + 2 * ND;
    float* T0 = o2;  // initial total lives in out[2] until b=0 consumes it

    const int TPB = 256;
    const long v4_blocks   = (ND / 4 + TPB - 1) / TPB;
    const long edge_blocks = (N_EDGES + TPB - 1) / TPB;
    const long row_blocks  = ((long)N_NODES + 15) / 16;  // 16 rows/block

    concat_kernel<<<v4_blocks, TPB, 0, stream>>>((const float4*)user_emb,
                                                 (const float4*)item_emb, (float4*)T0);

    // Per-behavior buffer rotation: {Tin, P(y1), Q(y2), Dst}
    float* Tins[3] = { T0, o0, o1 };
    float* Ps[3]   = { A,  A,  o2 };
    float* Qs[3]   = { o1, o2, A  };
    float* Dsts[3] = { o0, o1, o2 };

    for (int b = 0; b < 3; ++b) {
        const int*   rb = rows    + (long)b * N_EDGES;
        const int*   cb = cols    + (long)b * N_EDGES;
        const float* wb = weights + (long)b * N_EDGES;
        const float4* Tin = (const float4*)Tins[b];
        float4* P   = (float4*)Ps[b];
        float4* Q   = (float4*)Qs[b];
        float4* Dst = (float4*)Dsts[b];

        // --- build CSR (row-sorted packed edges), reused by all 3 layers ---
        hipMemsetAsync(cnt, 0, (size_t)N_NODES * sizeof(int), stream);
        hist_kernel<<<edge_blocks, TPB, 0, stream>>>(rb, cnt);
        scan1_kernel<<<NB_SCAN, 256, 0, stream>>>(cnt, excl, partials);
        scan2_kernel<<<1, 1024, 0, stream>>>(partials);
        scan3_kernel<<<NB_SCAN, 256, 0, stream>>>(excl, partials, rowptr, cursor);
        scatter_kernel<<<edge_blocks, TPB, 0, stream>>>(rb, cb, wb, cursor, sedge);

        // --- 3 LightGCN layers (layer 3 fused with accumulate+normalize) ---
        spmm_csr_kernel<<<row_blocks, TPB, 0, stream>>>(rowptr, sedge, Tin, P);
        spmm_csr_kernel<<<row_blocks, TPB, 0, stream>>>(rowptr, sedge,
                                                        (const float4*)P, Q);
        spmm_final_kernel<<<row_blocks, TPB, 0, stream>>>(rowptr, sedge,
                                                          (const float4*)Q, Tin,
                                                          (const float4*)P,
                                                          (const float4*)Q, Dst);
    }
}

// Round 4
// 908.436 us; speedup vs baseline: 2.9212x; 1.0414x over previous
//
#include <hip/hip_runtime.h>
#include <math.h>

#define N_USERS 100000
#define N_ITEMS 100000
#define EMB 64
#define N_NODES (N_USERS + N_ITEMS + 2)   // 200002
#define N_EDGES 1200000
#define E3 (3 * N_EDGES)                  // 3,600,000
#define N3 (3 * N_NODES)                  // 600,006
#define ND ((long)N_NODES * (long)EMB)    // 12,800,128
#define NB_SCAN1 ((N3 + 255) / 256)       // 2344

typedef float f32x4 __attribute__((ext_vector_type(4)));

__device__ inline void fma4(float4& acc, float w, const float4 v) {
    acc.x = fmaf(w, v.x, acc.x);
    acc.y = fmaf(w, v.y, acc.y);
    acc.z = fmaf(w, v.z, acc.z);
    acc.w = fmaf(w, v.w, acc.w);
}

// Build total = concat(user_emb, item_emb), vectorized float4
__global__ void concat_kernel(const float4* __restrict__ u,
                              const float4* __restrict__ it,
                              float4* __restrict__ t) {
    long i = (long)blockIdx.x * blockDim.x + threadIdx.x;  // over ND/4
    if (i >= ND / 4) return;
    long n = i >> 4;  // 16 float4 per 64-float row
    if (n < (long)(N_USERS + 1)) t[i] = u[i];
    else                         t[i] = it[i - (long)(N_USERS + 1) * 16];
}

// fused histogram for all 3 behaviors: cnt[b][n]
__global__ void hist3_kernel(const int* __restrict__ rows, int* __restrict__ cnt) {
    int e = blockIdx.x * blockDim.x + threadIdx.x;
    if (e >= E3) return;
    int b = (e >= 2 * N_EDGES) ? 2 : ((e >= N_EDGES) ? 1 : 0);
    atomicAdd(&cnt[b * N_NODES + rows[e]], 1);
}

// scan step 1 over flattened [3*N_NODES] counts: per-block excl scan + totals
__global__ void scan1_kernel(const int* __restrict__ cnt, int* __restrict__ excl,
                             int* __restrict__ partials) {
    __shared__ int sm[256];
    int tid = threadIdx.x;
    int i = blockIdx.x * 256 + tid;
    int v = (i < N3) ? cnt[i] : 0;
    sm[tid] = v;
    __syncthreads();
    for (int off = 1; off < 256; off <<= 1) {
        int t = (tid >= off) ? sm[tid - off] : 0;
        __syncthreads();
        sm[tid] += t;
        __syncthreads();
    }
    if (i < N3) excl[i] = sm[tid] - v;
    if (tid == 255) partials[blockIdx.x] = sm[255];
}

// scan step 2: exclusive scan of NB_SCAN1 (=2344) block totals, one block + carry loop
__global__ void scan2_kernel(int* __restrict__ partials) {
    __shared__ int sm[1024];
    __shared__ int carry;
    int tid = threadIdx.x;
    if (tid == 0) carry = 0;
    __syncthreads();
    for (int base = 0; base < NB_SCAN1; base += 1024) {
        int i = base + tid;
        int v = (i < NB_SCAN1) ? partials[i] : 0;
        sm[tid] = v;
        __syncthreads();
        for (int off = 1; off < 1024; off <<= 1) {
            int t = (tid >= off) ? sm[tid - off] : 0;
            __syncthreads();
            sm[tid] += t;
            __syncthreads();
        }
        int excl = sm[tid] - v + carry;
        if (i < NB_SCAN1) partials[i] = excl;
        __syncthreads();
        if (tid == 0) carry += sm[1023];
        __syncthreads();
    }
}

// scan step 3: finalize rowptr (global offsets into sedge) and scatter cursors
__global__ void scan3_kernel(const int* __restrict__ excl, const int* __restrict__ partials,
                             int* __restrict__ rowptr, int* __restrict__ cursor) {
    int i = blockIdx.x * 256 + threadIdx.x;
    if (i < N3) {
        int v = excl[i] + partials[blockIdx.x];
        rowptr[i] = v;
        cursor[i] = v;
    }
    if (i == 0) rowptr[N3] = E3;
}

// fused counting-sort scatter for all 3 behaviors
__global__ void scatter3_kernel(const int* __restrict__ rows, const int* __restrict__ cols,
                                const float* __restrict__ w, int* __restrict__ cursor,
                                int2* __restrict__ sedge) {
    int e = blockIdx.x * blockDim.x + threadIdx.x;
    if (e >= E3) return;
    int b = (e >= 2 * N_EDGES) ? 2 : ((e >= N_EDGES) ? 1 : 0);
    int p = atomicAdd(&cursor[b * N_NODES + rows[e]], 1);
    int2 pk;
    pk.x = cols[e];
    pk.y = __float_as_int(w[e]);
    sedge[p] = pk;
}

// CSR SpMM: 16 lanes (float4 each) per row, 4 rows/wave; unroll 4+2+1 for MLP.
__global__ void spmm_csr_kernel(const int* __restrict__ rowptr,
                                const int2* __restrict__ sedge,
                                const float4* __restrict__ x,
                                float* __restrict__ y) {
    int wid  = threadIdx.x >> 6;
    int lane = threadIdx.x & 63;
    int r = lane >> 4;
    int q = lane & 15;
    int n = (blockIdx.x * 4 + wid) * 4 + r;
    if (n >= N_NODES) return;
    int s = rowptr[n], e = rowptr[n + 1];
    float4 acc = make_float4(0.f, 0.f, 0.f, 0.f);
    int i = s;
    for (; i + 4 <= e; i += 4) {
        int2 e0 = sedge[i], e1 = sedge[i + 1], e2 = sedge[i + 2], e3 = sedge[i + 3];
        float4 v0 = x[(long)e0.x * 16 + q];
        float4 v1 = x[(long)e1.x * 16 + q];
        float4 v2 = x[(long)e2.x * 16 + q];
        float4 v3 = x[(long)e3.x * 16 + q];
        fma4(acc, __int_as_float(e0.y), v0);
        fma4(acc, __int_as_float(e1.y), v1);
        fma4(acc, __int_as_float(e2.y), v2);
        fma4(acc, __int_as_float(e3.y), v3);
    }
    if (i + 2 <= e) {
        int2 e0 = sedge[i], e1 = sedge[i + 1];
        float4 v0 = x[(long)e0.x * 16 + q];
        float4 v1 = x[(long)e1.x * 16 + q];
        fma4(acc, __int_as_float(e0.y), v0);
        fma4(acc, __int_as_float(e1.y), v1);
        i += 2;
    }
    if (i < e) {
        int2 e0 = sedge[i];
        float4 v0 = x[(long)e0.x * 16 + q];
        fma4(acc, __int_as_float(e0.y), v0);
    }
    f32x4 o = { acc.x, acc.y, acc.z, acc.w };
    __builtin_nontemporal_store(o, (f32x4*)&y[((long)n * 16 + q) * 4]);
}

// Fused layer 3 + epilogue: y3 = spmm(y2); v = (Tin + y1 + y2 + y3)/4;
// out = v / max(||v||, eps) + Tin.  `out` may alias P or Tin (own-row) but NOT Q/x.
__global__ void spmm_final_kernel(const int* __restrict__ rowptr,
                                  const int2* __restrict__ sedge,
                                  const float4* __restrict__ x,   // = Q (y2)
                                  const float4* __restrict__ Tin,
                                  const float4* P,                 // y1
                                  const float4* __restrict__ Q,    // y2
                                  float* out) {
    int wid  = threadIdx.x >> 6;
    int lane = threadIdx.x & 63;
    int r = lane >> 4;
    int q = lane & 15;
    int n = (blockIdx.x * 4 + wid) * 4 + r;
    if (n >= N_NODES) return;
    int s = rowptr[n], e = rowptr[n + 1];
    float4 acc = make_float4(0.f, 0.f, 0.f, 0.f);
    int i = s;
    for (; i + 4 <= e; i += 4) {
        int2 e0 = sedge[i], e1 = sedge[i + 1], e2 = sedge[i + 2], e3 = sedge[i + 3];
        float4 v0 = x[(long)e0.x * 16 + q];
        float4 v1 = x[(long)e1.x * 16 + q];
        float4 v2 = x[(long)e2.x * 16 + q];
        float4 v3 = x[(long)e3.x * 16 + q];
        fma4(acc, __int_as_float(e0.y), v0);
        fma4(acc, __int_as_float(e1.y), v1);
        fma4(acc, __int_as_float(e2.y), v2);
        fma4(acc, __int_as_float(e3.y), v3);
    }
    if (i + 2 <= e) {
        int2 e0 = sedge[i], e1 = sedge[i + 1];
        float4 v0 = x[(long)e0.x * 16 + q];
        float4 v1 = x[(long)e1.x * 16 + q];
        fma4(acc, __int_as_float(e0.y), v0);
        fma4(acc, __int_as_float(e1.y), v1);
        i += 2;
    }
    if (i < e) {
        int2 e0 = sedge[i];
        float4 v0 = x[(long)e0.x * 16 + q];
        fma4(acc, __int_as_float(e0.y), v0);
    }
    long o = (long)n * 16 + q;
    float4 t = Tin[o];
    float4 p = P[o];
    float4 qq = Q[o];
    float4 v;
    v.x = (t.x + p.x + qq.x + acc.x) * 0.25f;
    v.y = (t.y + p.y + qq.y + acc.y) * 0.25f;
    v.z = (t.z + p.z + qq.z + acc.z) * 0.25f;
    v.w = (t.w + p.w + qq.w + acc.w) * 0.25f;
    float ss = v.x * v.x + v.y * v.y + v.z * v.z + v.w * v.w;
    #pragma unroll
    for (int off = 1; off < 16; off <<= 1) ss += __shfl_xor(ss, off, 64);
    float inv = 1.0f / fmaxf(sqrtf(ss), 1e-12f);
    f32x4 ov = { v.x * inv + t.x, v.y * inv + t.y, v.z * inv + t.z, v.w * inv + t.w };
    __builtin_nontemporal_store(ov, (f32x4*)&out[o * 4]);
}

extern "C" void kernel_launch(void* const* d_in, const int* in_sizes, int n_in,
                              void* d_out, int out_size, void* d_ws, size_t ws_size,
                              hipStream_t stream) {
    const float* user_emb = (const float*)d_in[0];
    const float* item_emb = (const float*)d_in[1];
    const int*   rows     = (const int*)d_in[2];
    const int*   cols     = (const int*)d_in[3];
    const float* weights  = (const float*)d_in[4];
    float* out = (float*)d_out;

    // Workspace carve-up (~90 MB)
    float* A        = (float*)d_ws;             // ND floats
    int2*  sedge    = (int2*)(A + ND);          // E3 packed (col,w), row-sorted, global
    int*   rowptr   = (int*)(sedge + E3);       // N3+1 (+pad)
    int*   cursor   = rowptr + N3 + 2;          // N3
    int*   cnt      = cursor + N3;              // N3
    int*   excl     = cnt + N3;                 // N3
    int*   partials = excl + N3;                // NB_SCAN1 (+pad)

    float* o0 = out;
    float* o1 = out + ND;
    float* o2 = out + 2 * ND;
    float* T0 = o2;  // initial total lives in out[2] until b=0 consumes it

    const int TPB = 256;
    const long v4_blocks   = (ND / 4 + TPB - 1) / TPB;
    const long e3_blocks   = (E3 + TPB - 1) / TPB;
    const long row_blocks  = ((long)N_NODES + 15) / 16;  // 16 rows/block

    // --- build all 3 CSRs in fused passes ---
    hipMemsetAsync(cnt, 0, (size_t)N3 * sizeof(int), stream);
    hist3_kernel<<<e3_blocks, TPB, 0, stream>>>(rows, cnt);
    scan1_kernel<<<NB_SCAN1, 256, 0, stream>>>(cnt, excl, partials);
    scan2_kernel<<<1, 1024, 0, stream>>>(partials);
    scan3_kernel<<<NB_SCAN1, 256, 0, stream>>>(excl, partials, rowptr, cursor);
    scatter3_kernel<<<e3_blocks, TPB, 0, stream>>>(rows, cols, weights, cursor, sedge);

    concat_kernel<<<v4_blocks, TPB, 0, stream>>>((const float4*)user_emb,
                                                 (const float4*)item_emb, (float4*)T0);

    // Per-behavior buffer rotation: {Tin, P(y1), Q(y2), Dst}
    float* Tins[3] = { T0, o0, o1 };
    float* Ps[3]   = { A,  A,  o2 };
    float* Qs[3]   = { o1, o2, A  };
    float* Dsts[3] = { o0, o1, o2 };

    for (int b = 0; b < 3; ++b) {
        const int* rp = rowptr + (long)b * N_NODES;
        const float4* Tin = (const float4*)Tins[b];
        float* P   = Ps[b];
        float* Q   = Qs[b];
        float* Dst = Dsts[b];

        spmm_csr_kernel<<<row_blocks, TPB, 0, stream>>>(rp, sedge, Tin, P);
        spmm_csr_kernel<<<row_blocks, TPB, 0, stream>>>(rp, sedge,
                                                        (const float4*)P, Q);
        spmm_final_kernel<<<row_blocks, TPB, 0, stream>>>(rp, sedge,
                                                          (const float4*)Q, Tin,
                                                          (const float4*)P,
                                                          (const float4*)Q, Dst);
    }
}

// Round 5
// 685.785 us; speedup vs baseline: 3.8697x; 1.3247x over previous
//
#include <hip/hip_runtime.h>
#include <math.h>

#define N_USERS 100000
#define N_ITEMS 100000
#define EMB 64
#define N_NODES (N_USERS + N_ITEMS + 2)   // 200002
#define N_EDGES 1200000
#define E3 (3 * N_EDGES)                  // 3,600,000
#define N3 (3 * N_NODES)                  // 600,006
#define ND ((long)N_NODES * (long)EMB)    // 12,800,128

#define BUCKET_BITS 9
#define KPB 512                           // keys per bucket
#define NBUCKET ((N3 + KPB - 1) / KPB)    // 1172
#define EPB 4096                          // edges per pass-1 block
#define NB_P1 ((E3 + EPB - 1) / EPB)      // 879

typedef float f32x4 __attribute__((ext_vector_type(4)));

__device__ inline void fma4(float4& acc, float w, const float4 v) {
    acc.x = fmaf(w, v.x, acc.x);
    acc.y = fmaf(w, v.y, acc.y);
    acc.z = fmaf(w, v.z, acc.z);
    acc.w = fmaf(w, v.w, acc.w);
}

// Build total = concat(user_emb, item_emb), vectorized float4
__global__ void concat_kernel(const float4* __restrict__ u,
                              const float4* __restrict__ it,
                              float4* __restrict__ t) {
    long i = (long)blockIdx.x * blockDim.x + threadIdx.x;  // over ND/4
    if (i >= ND / 4) return;
    long n = i >> 4;
    if (n < (long)(N_USERS + 1)) t[i] = u[i];
    else                         t[i] = it[i - (long)(N_USERS + 1) * 16];
}

// --- sort stage 1: coarse bucket histogram (LDS-aggregated) ---
__global__ void bucket_hist_kernel(const int* __restrict__ rows, int* __restrict__ bcnt) {
    __shared__ int h[NBUCKET];
    for (int i = threadIdx.x; i < NBUCKET; i += 256) h[i] = 0;
    __syncthreads();
    long base = (long)blockIdx.x * EPB;
    for (int k = 0; k < EPB / 256; ++k) {
        long e = base + k * 256 + threadIdx.x;
        if (e < E3) {
            int b = (e >= 2L * N_EDGES) ? 2 : ((e >= N_EDGES) ? 1 : 0);
            int key = b * N_NODES + rows[e];
            atomicAdd(&h[key >> BUCKET_BITS], 1);
        }
    }
    __syncthreads();
    for (int i = threadIdx.x; i < NBUCKET; i += 256)
        if (h[i]) atomicAdd(&bcnt[i], h[i]);
}

// --- sort stage 2: exclusive scan of 1172 bucket counts (1 block) ---
__global__ void bucket_scan_kernel(const int* __restrict__ bcnt, int* __restrict__ bbase,
                                   int* __restrict__ bcur, int* __restrict__ rowptr) {
    __shared__ int sm[1024];
    __shared__ int carry;
    int tid = threadIdx.x;
    if (tid == 0) carry = 0;
    __syncthreads();
    for (int base = 0; base < NBUCKET; base += 1024) {
        int i = base + tid;
        int v = (i < NBUCKET) ? bcnt[i] : 0;
        sm[tid] = v;
        __syncthreads();
        for (int off = 1; off < 1024; off <<= 1) {
            int t = (tid >= off) ? sm[tid - off] : 0;
            __syncthreads();
            sm[tid] += t;
            __syncthreads();
        }
        if (i < NBUCKET) { int ex = sm[tid] - v + carry; bbase[i] = ex; bcur[i] = ex; }
        __syncthreads();
        if (tid == 0) carry += sm[1023];
        __syncthreads();
    }
    if (tid == 0) { bbase[NBUCKET] = E3; rowptr[N3] = E3; }
}

// --- sort stage 3: bucket-grouping scatter, per-block LDS aggregation ---
// Each block's writes to a bucket are contiguous bursts -> line-local.
__global__ void bucket_scatter_kernel(const int* __restrict__ rows,
                                      const int* __restrict__ cols,
                                      const float* __restrict__ w,
                                      int* __restrict__ bcur,
                                      int2* __restrict__ tmpedge) {
    __shared__ int h[NBUCKET];
    __shared__ int lbase[NBUCKET];
    for (int i = threadIdx.x; i < NBUCKET; i += 256) h[i] = 0;
    __syncthreads();
    long base = (long)blockIdx.x * EPB;
    int keys[EPB / 256];
    for (int k = 0; k < EPB / 256; ++k) {
        long e = base + k * 256 + threadIdx.x;
        int key = -1;
        if (e < E3) {
            int b = (e >= 2L * N_EDGES) ? 2 : ((e >= N_EDGES) ? 1 : 0);
            key = b * N_NODES + rows[e];
            atomicAdd(&h[key >> BUCKET_BITS], 1);
        }
        keys[k] = key;
    }
    __syncthreads();
    for (int i = threadIdx.x; i < NBUCKET; i += 256) {
        int c = h[i];
        lbase[i] = c ? atomicAdd(&bcur[i], c) : 0;
        h[i] = 0;
    }
    __syncthreads();
    for (int k = 0; k < EPB / 256; ++k) {
        long e = base + k * 256 + threadIdx.x;
        int key = keys[k];
        if (key >= 0) {
            int bk = key >> BUCKET_BITS;
            int pos = lbase[bk] + atomicAdd(&h[bk], 1);
            int2 pk;
            pk.x = ((key & (KPB - 1)) << 18) | cols[e];  // col < 2^18
            pk.y = __float_as_int(w[e]);
            tmpedge[pos] = pk;
        }
    }
}

// --- sort stage 4: in-bucket counting sort + rowptr emission ---
// One block per bucket; writes land within the bucket's ~24KB span.
__global__ void bucket_sort_kernel(const int* __restrict__ bbase,
                                   const int2* __restrict__ tmpedge,
                                   int2* __restrict__ sedge,
                                   int* __restrict__ rowptr) {
    int g = blockIdx.x;
    int s = bbase[g], e = bbase[g + 1];
    __shared__ int h[KPB];
    __shared__ int ex[KPB];
    __shared__ int tmp[256];
    int tid = threadIdx.x;
    h[tid * 2] = 0; h[tid * 2 + 1] = 0;
    __syncthreads();
    for (int i = s + tid; i < e; i += 256) atomicAdd(&h[tmpedge[i].x >> 18], 1);
    __syncthreads();
    // exclusive scan over 512 via pair-sum + Hillis-Steele over 256
    int a0 = h[tid * 2], a1 = h[tid * 2 + 1];
    int psum = a0 + a1;
    tmp[tid] = psum;
    __syncthreads();
    for (int off = 1; off < 256; off <<= 1) {
        int t = (tid >= off) ? tmp[tid - off] : 0;
        __syncthreads();
        tmp[tid] += t;
        __syncthreads();
    }
    int pex = tmp[tid] - psum;
    ex[tid * 2] = pex;
    ex[tid * 2 + 1] = pex + a0;
    __syncthreads();
    // coalesced rowptr slice for this bucket's 512 keys
    for (int j = tid; j < KPB; j += 256) {
        int key = g * KPB + j;
        if (key < N3) rowptr[key] = s + ex[j];
    }
    // reuse h as per-key cursor
    h[tid * 2] = ex[tid * 2];
    h[tid * 2 + 1] = ex[tid * 2 + 1];
    __syncthreads();
    for (int i = s + tid; i < e; i += 256) {
        int2 pk = tmpedge[i];
        int kl = pk.x >> 18;
        int pos = s + atomicAdd(&h[kl], 1);
        int2 o;
        o.x = pk.x & 0x3FFFF;
        o.y = pk.y;
        sedge[pos] = o;
    }
}

// CSR SpMM: 16 lanes (float4 each) per row, 4 rows/wave; unroll 4+2+1 for MLP.
__global__ void spmm_csr_kernel(const int* __restrict__ rowptr,
                                const int2* __restrict__ sedge,
                                const float4* __restrict__ x,
                                float* __restrict__ y) {
    int wid  = threadIdx.x >> 6;
    int lane = threadIdx.x & 63;
    int r = lane >> 4;
    int q = lane & 15;
    int n = (blockIdx.x * 4 + wid) * 4 + r;
    if (n >= N_NODES) return;
    int s = rowptr[n], e = rowptr[n + 1];
    float4 acc = make_float4(0.f, 0.f, 0.f, 0.f);
    int i = s;
    for (; i + 4 <= e; i += 4) {
        int2 e0 = sedge[i], e1 = sedge[i + 1], e2 = sedge[i + 2], e3 = sedge[i + 3];
        float4 v0 = x[(long)e0.x * 16 + q];
        float4 v1 = x[(long)e1.x * 16 + q];
        float4 v2 = x[(long)e2.x * 16 + q];
        float4 v3 = x[(long)e3.x * 16 + q];
        fma4(acc, __int_as_float(e0.y), v0);
        fma4(acc, __int_as_float(e1.y), v1);
        fma4(acc, __int_as_float(e2.y), v2);
        fma4(acc, __int_as_float(e3.y), v3);
    }
    if (i + 2 <= e) {
        int2 e0 = sedge[i], e1 = sedge[i + 1];
        float4 v0 = x[(long)e0.x * 16 + q];
        float4 v1 = x[(long)e1.x * 16 + q];
        fma4(acc, __int_as_float(e0.y), v0);
        fma4(acc, __int_as_float(e1.y), v1);
        i += 2;
    }
    if (i < e) {
        int2 e0 = sedge[i];
        float4 v0 = x[(long)e0.x * 16 + q];
        fma4(acc, __int_as_float(e0.y), v0);
    }
    f32x4 o = { acc.x, acc.y, acc.z, acc.w };
    __builtin_nontemporal_store(o, (f32x4*)&y[((long)n * 16 + q) * 4]);
}

// Fused layer 3 + epilogue: y3 = spmm(y2); v = (Tin + y1 + y2 + y3)/4;
// out = v / max(||v||, eps) + Tin.  `out` may alias P or Tin (own-row) but NOT Q/x.
__global__ void spmm_final_kernel(const int* __restrict__ rowptr,
                                  const int2* __restrict__ sedge,
                                  const float4* __restrict__ x,   // = Q (y2)
                                  const float4* __restrict__ Tin,
                                  const float4* P,                 // y1
                                  const float4* __restrict__ Q,    // y2
                                  float* out) {
    int wid  = threadIdx.x >> 6;
    int lane = threadIdx.x & 63;
    int r = lane >> 4;
    int q = lane & 15;
    int n = (blockIdx.x * 4 + wid) * 4 + r;
    if (n >= N_NODES) return;
    int s = rowptr[n], e = rowptr[n + 1];
    float4 acc = make_float4(0.f, 0.f, 0.f, 0.f);
    int i = s;
    for (; i + 4 <= e; i += 4) {
        int2 e0 = sedge[i], e1 = sedge[i + 1], e2 = sedge[i + 2], e3 = sedge[i + 3];
        float4 v0 = x[(long)e0.x * 16 + q];
        float4 v1 = x[(long)e1.x * 16 + q];
        float4 v2 = x[(long)e2.x * 16 + q];
        float4 v3 = x[(long)e3.x * 16 + q];
        fma4(acc, __int_as_float(e0.y), v0);
        fma4(acc, __int_as_float(e1.y), v1);
        fma4(acc, __int_as_float(e2.y), v2);
        fma4(acc, __int_as_float(e3.y), v3);
    }
    if (i + 2 <= e) {
        int2 e0 = sedge[i], e1 = sedge[i + 1];
        float4 v0 = x[(long)e0.x * 16 + q];
        float4 v1 = x[(long)e1.x * 16 + q];
        fma4(acc, __int_as_float(e0.y), v0);
        fma4(acc, __int_as_float(e1.y), v1);
        i += 2;
    }
    if (i < e) {
        int2 e0 = sedge[i];
        float4 v0 = x[(long)e0.x * 16 + q];
        fma4(acc, __int_as_float(e0.y), v0);
    }
    long o = (long)n * 16 + q;
    float4 t = Tin[o];
    float4 p = P[o];
    float4 qq = Q[o];
    float4 v;
    v.x = (t.x + p.x + qq.x + acc.x) * 0.25f;
    v.y = (t.y + p.y + qq.y + acc.y) * 0.25f;
    v.z = (t.z + p.z + qq.z + acc.z) * 0.25f;
    v.w = (t.w + p.w + qq.w + acc.w) * 0.25f;
    float ss = v.x * v.x + v.y * v.y + v.z * v.z + v.w * v.w;
    #pragma unroll
    for (int off = 1; off < 16; off <<= 1) ss += __shfl_xor(ss, off, 64);
    float inv = 1.0f / fmaxf(sqrtf(ss), 1e-12f);
    f32x4 ov = { v.x * inv + t.x, v.y * inv + t.y, v.z * inv + t.z, v.w * inv + t.w };
    __builtin_nontemporal_store(ov, (f32x4*)&out[o * 4]);
}

extern "C" void kernel_launch(void* const* d_in, const int* in_sizes, int n_in,
                              void* d_out, int out_size, void* d_ws, size_t ws_size,
                              hipStream_t stream) {
    const float* user_emb = (const float*)d_in[0];
    const float* item_emb = (const float*)d_in[1];
    const int*   rows     = (const int*)d_in[2];
    const int*   cols     = (const int*)d_in[3];
    const float* weights  = (const float*)d_in[4];
    float* out = (float*)d_out;

    // Workspace carve-up (~83 MB). tmpedge aliases A (dead before first SpMM).
    float* A        = (float*)d_ws;             // ND floats (51.2 MB)
    int2*  tmpedge  = (int2*)d_ws;              // E3 int2 (28.8 MB) — alias of A
    int2*  sedge    = (int2*)(A + ND);          // E3 int2 (28.8 MB), final sorted
    int*   rowptr   = (int*)(sedge + E3);       // N3+1 (+pad)
    int*   bcnt     = rowptr + N3 + 2;          // NBUCKET
    int*   bbase    = bcnt + NBUCKET;           // NBUCKET+1
    int*   bcur     = bbase + NBUCKET + 1;      // NBUCKET

    float* o0 = out;
    float* o1 = out + ND;
    float* o2 = out + 2 * ND;
    float* T0 = o2;  // initial total lives in out[2] until b=0 consumes it

    const int TPB = 256;
    const long v4_blocks  = (ND / 4 + TPB - 1) / TPB;
    const long row_blocks = ((long)N_NODES + 15) / 16;  // 16 rows/block

    // --- build all 3 CSRs via two-level bucket sort ---
    hipMemsetAsync(bcnt, 0, (size_t)NBUCKET * sizeof(int), stream);
    bucket_hist_kernel<<<NB_P1, TPB, 0, stream>>>(rows, bcnt);
    bucket_scan_kernel<<<1, 1024, 0, stream>>>(bcnt, bbase, bcur, rowptr);
    bucket_scatter_kernel<<<NB_P1, TPB, 0, stream>>>(rows, cols, weights, bcur, tmpedge);
    bucket_sort_kernel<<<NBUCKET, TPB, 0, stream>>>(bbase, tmpedge, sedge, rowptr);

    concat_kernel<<<v4_blocks, TPB, 0, stream>>>((const float4*)user_emb,
                                                 (const float4*)item_emb, (float4*)T0);

    // Per-behavior buffer rotation: {Tin, P(y1), Q(y2), Dst}
    float* Tins[3] = { T0, o0, o1 };
    float* Ps[3]   = { A,  A,  o2 };
    float* Qs[3]   = { o1, o2, A  };
    float* Dsts[3] = { o0, o1, o2 };

    for (int b = 0; b < 3; ++b) {
        const int* rp = rowptr + (long)b * N_NODES;
        const float4* Tin = (const float4*)Tins[b];
        float* P   = Ps[b];
        float* Q   = Qs[b];
        float* Dst = Dsts[b];

        spmm_csr_kernel<<<row_blocks, TPB, 0, stream>>>(rp, sedge, Tin, P);
        spmm_csr_kernel<<<row_blocks, TPB, 0, stream>>>(rp, sedge,
                                                        (const float4*)P, Q);
        spmm_final_kernel<<<row_blocks, TPB, 0, stream>>>(rp, sedge,
                                                          (const float4*)Q, Tin,
                                                          (const float4*)P,
                                                          (const float4*)Q, Dst);
    }
}

// Round 7
// 551.214 us; speedup vs baseline: 4.8144x; 1.2441x over previous
//
#include <hip/hip_runtime.h>
#include <math.h>

#define N_USERS 100000
#define N_ITEMS 100000
#define EMB 64
#define N_NODES (N_USERS + N_ITEMS + 2)   // 200002
#define N_EDGES 1200000
#define E3 (3 * N_EDGES)                  // 3,600,000
#define N3 (3 * N_NODES)                  // 600,006
#define ND ((long)N_NODES * (long)EMB)    // 12,800,128

#define BUCKET_BITS 9
#define KPB 512                           // keys per bucket
#define NBUCKET ((N3 + KPB - 1) / KPB)    // 1172
#define EPB 4096                          // edges per pass-1 block
#define NB_P1 ((E3 + EPB - 1) / EPB)      // 879

typedef float f32x4 __attribute__((ext_vector_type(4)));
typedef unsigned short u16x4 __attribute__((ext_vector_type(4)));

__device__ inline void fma4(float4& acc, float w, const float4 v) {
    acc.x = fmaf(w, v.x, acc.x);
    acc.y = fmaf(w, v.y, acc.y);
    acc.z = fmaf(w, v.z, acc.z);
    acc.w = fmaf(w, v.w, acc.w);
}

__device__ inline unsigned short f2bf(float f) {   // RTNE
    unsigned int u = __float_as_uint(f);
    unsigned int r = (u + 0x7FFFu + ((u >> 16) & 1u)) >> 16;
    return (unsigned short)r;
}
__device__ inline float bf2f(unsigned short s) {
    return __uint_as_float((unsigned int)s << 16);
}
__device__ inline float4 bf4_to_f4(u16x4 s) {
    float4 f;
    f.x = bf2f(s.x); f.y = bf2f(s.y); f.z = bf2f(s.z); f.w = bf2f(s.w);
    return f;
}
__device__ inline u16x4 f4_to_bf4(float4 f) {
    u16x4 s;
    s.x = f2bf(f.x); s.y = f2bf(f.y); s.z = f2bf(f.z); s.w = f2bf(f.w);
    return s;
}

// Build total = concat(user_emb, item_emb), vectorized float4
__global__ void concat_kernel(const float4* __restrict__ u,
                              const float4* __restrict__ it,
                              float4* __restrict__ t) {
    long i = (long)blockIdx.x * blockDim.x + threadIdx.x;  // over ND/4
    if (i >= ND / 4) return;
    long n = i >> 4;
    if (n < (long)(N_USERS + 1)) t[i] = u[i];
    else                         t[i] = it[i - (long)(N_USERS + 1) * 16];
}

__global__ void zero_bcnt_kernel(int* __restrict__ bcnt) {
    int i = blockIdx.x * blockDim.x + threadIdx.x;
    if (i < NBUCKET) bcnt[i] = 0;
}

// --- sort stage 1: coarse bucket histogram (LDS-aggregated), 512 threads ---
__global__ void bucket_hist_kernel(const int* __restrict__ rows, int* __restrict__ bcnt) {
    __shared__ int h[NBUCKET];
    for (int i = threadIdx.x; i < NBUCKET; i += 512) h[i] = 0;
    __syncthreads();
    long base = (long)blockIdx.x * EPB;
    for (int k = 0; k < EPB / 512; ++k) {
        long e = base + k * 512 + threadIdx.x;
        if (e < E3) {
            int b = (e >= 2L * N_EDGES) ? 2 : ((e >= N_EDGES) ? 1 : 0);
            int key = b * N_NODES + rows[e];
            atomicAdd(&h[key >> BUCKET_BITS], 1);
        }
    }
    __syncthreads();
    for (int i = threadIdx.x; i < NBUCKET; i += 512)
        if (h[i]) atomicAdd(&bcnt[i], h[i]);
}

// --- sort stage 2: exclusive scan of 1172 bucket counts (1 block) ---
__global__ void bucket_scan_kernel(const int* __restrict__ bcnt, int* __restrict__ bbase,
                                   int* __restrict__ bcur, int* __restrict__ rowptr) {
    __shared__ int sm[1024];
    __shared__ int carry;
    int tid = threadIdx.x;
    if (tid == 0) carry = 0;
    __syncthreads();
    for (int base = 0; base < NBUCKET; base += 1024) {
        int i = base + tid;
        int v = (i < NBUCKET) ? bcnt[i] : 0;
        sm[tid] = v;
        __syncthreads();
        for (int off = 1; off < 1024; off <<= 1) {
            int t = (tid >= off) ? sm[tid - off] : 0;
            __syncthreads();
            sm[tid] += t;
            __syncthreads();
        }
        if (i < NBUCKET) { int ex = sm[tid] - v + carry; bbase[i] = ex; bcur[i] = ex; }
        __syncthreads();
        if (tid == 0) carry += sm[1023];
        __syncthreads();
    }
    if (tid == 0) { bbase[NBUCKET] = E3; rowptr[N3] = E3; }
}

// --- sort stage 3: bucket-grouping scatter, per-block LDS aggregation, 512 thr ---
__global__ void bucket_scatter_kernel(const int* __restrict__ rows,
                                      const int* __restrict__ cols,
                                      const float* __restrict__ w,
                                      int* __restrict__ bcur,
                                      int2* __restrict__ tmpedge) {
    __shared__ int h[NBUCKET];
    __shared__ int lbase[NBUCKET];
    for (int i = threadIdx.x; i < NBUCKET; i += 512) h[i] = 0;
    __syncthreads();
    long base = (long)blockIdx.x * EPB;
    int keys[EPB / 512];
    for (int k = 0; k < EPB / 512; ++k) {
        long e = base + k * 512 + threadIdx.x;
        int key = -1;
        if (e < E3) {
            int b = (e >= 2L * N_EDGES) ? 2 : ((e >= N_EDGES) ? 1 : 0);
            key = b * N_NODES + rows[e];
            atomicAdd(&h[key >> BUCKET_BITS], 1);
        }
        keys[k] = key;
    }
    __syncthreads();
    for (int i = threadIdx.x; i < NBUCKET; i += 512) {
        int c = h[i];
        lbase[i] = c ? atomicAdd(&bcur[i], c) : 0;
        h[i] = 0;
    }
    __syncthreads();
    for (int k = 0; k < EPB / 512; ++k) {
        long e = base + k * 512 + threadIdx.x;
        int key = keys[k];
        if (key >= 0) {
            int bk = key >> BUCKET_BITS;
            int pos = lbase[bk] + atomicAdd(&h[bk], 1);
            int2 pk;
            pk.x = ((key & (KPB - 1)) << 18) | cols[e];  // col < 2^18
            pk.y = __float_as_int(w[e]);
            tmpedge[pos] = pk;
        }
    }
}

// --- sort stage 4: in-bucket counting sort + rowptr emission ---
__global__ void bucket_sort_kernel(const int* __restrict__ bbase,
                                   const int2* __restrict__ tmpedge,
                                   int2* __restrict__ sedge,
                                   int* __restrict__ rowptr) {
    int g = blockIdx.x;
    int s = bbase[g], e = bbase[g + 1];
    __shared__ int h[KPB];
    __shared__ int ex[KPB];
    __shared__ int tmp[256];
    int tid = threadIdx.x;
    h[tid * 2] = 0; h[tid * 2 + 1] = 0;
    __syncthreads();
    for (int i = s + tid; i < e; i += 256) atomicAdd(&h[tmpedge[i].x >> 18], 1);
    __syncthreads();
    int a0 = h[tid * 2], a1 = h[tid * 2 + 1];
    int psum = a0 + a1;
    tmp[tid] = psum;
    __syncthreads();
    for (int off = 1; off < 256; off <<= 1) {
        int t = (tid >= off) ? tmp[tid - off] : 0;
        __syncthreads();
        tmp[tid] += t;
        __syncthreads();
    }
    int pex = tmp[tid] - psum;
    ex[tid * 2] = pex;
    ex[tid * 2 + 1] = pex + a0;
    __syncthreads();
    for (int j = tid; j < KPB; j += 256) {
        int key = g * KPB + j;
        if (key < N3) rowptr[key] = s + ex[j];
    }
    h[tid * 2] = ex[tid * 2];
    h[tid * 2 + 1] = ex[tid * 2 + 1];
    __syncthreads();
    for (int i = s + tid; i < e; i += 256) {
        int2 pk = tmpedge[i];
        int kl = pk.x >> 18;
        int pos = s + atomicAdd(&h[kl], 1);
        int2 o;
        o.x = pk.x & 0x3FFFF;
        o.y = pk.y;
        sedge[pos] = o;
    }
}

// Layer 1: gather f32 x, write bf16 y.
__global__ void spmm_f32_bf16_kernel(const int* __restrict__ rowptr,
                                     const int2* __restrict__ sedge,
                                     const float4* __restrict__ x,
                                     u16x4* __restrict__ y) {
    int wid  = threadIdx.x >> 6;
    int lane = threadIdx.x & 63;
    int r = lane >> 4;
    int q = lane & 15;
    int n = (blockIdx.x * 4 + wid) * 4 + r;
    if (n >= N_NODES) return;
    int s = rowptr[n], e = rowptr[n + 1];
    float4 acc = make_float4(0.f, 0.f, 0.f, 0.f);
    int i = s;
    for (; i + 4 <= e; i += 4) {
        int2 e0 = sedge[i], e1 = sedge[i + 1], e2 = sedge[i + 2], e3 = sedge[i + 3];
        float4 v0 = x[(long)e0.x * 16 + q];
        float4 v1 = x[(long)e1.x * 16 + q];
        float4 v2 = x[(long)e2.x * 16 + q];
        float4 v3 = x[(long)e3.x * 16 + q];
        fma4(acc, __int_as_float(e0.y), v0);
        fma4(acc, __int_as_float(e1.y), v1);
        fma4(acc, __int_as_float(e2.y), v2);
        fma4(acc, __int_as_float(e3.y), v3);
    }
    if (i + 2 <= e) {
        int2 e0 = sedge[i], e1 = sedge[i + 1];
        float4 v0 = x[(long)e0.x * 16 + q];
        float4 v1 = x[(long)e1.x * 16 + q];
        fma4(acc, __int_as_float(e0.y), v0);
        fma4(acc, __int_as_float(e1.y), v1);
        i += 2;
    }
    if (i < e) {
        int2 e0 = sedge[i];
        float4 v0 = x[(long)e0.x * 16 + q];
        fma4(acc, __int_as_float(e0.y), v0);
    }
    __builtin_nontemporal_store(f4_to_bf4(acc), &y[(long)n * 16 + q]);
}

// Layer 2: gather bf16 x, write bf16 y.
__global__ void spmm_bf16_bf16_kernel(const int* __restrict__ rowptr,
                                      const int2* __restrict__ sedge,
                                      const u16x4* __restrict__ x,
                                      u16x4* __restrict__ y) {
    int wid  = threadIdx.x >> 6;
    int lane = threadIdx.x & 63;
    int r = lane >> 4;
    int q = lane & 15;
    int n = (blockIdx.x * 4 + wid) * 4 + r;
    if (n >= N_NODES) return;
    int s = rowptr[n], e = rowptr[n + 1];
    float4 acc = make_float4(0.f, 0.f, 0.f, 0.f);
    int i = s;
    for (; i + 4 <= e; i += 4) {
        int2 e0 = sedge[i], e1 = sedge[i + 1], e2 = sedge[i + 2], e3 = sedge[i + 3];
        u16x4 b0 = x[(long)e0.x * 16 + q];
        u16x4 b1 = x[(long)e1.x * 16 + q];
        u16x4 b2 = x[(long)e2.x * 16 + q];
        u16x4 b3 = x[(long)e3.x * 16 + q];
        fma4(acc, __int_as_float(e0.y), bf4_to_f4(b0));
        fma4(acc, __int_as_float(e1.y), bf4_to_f4(b1));
        fma4(acc, __int_as_float(e2.y), bf4_to_f4(b2));
        fma4(acc, __int_as_float(e3.y), bf4_to_f4(b3));
    }
    if (i + 2 <= e) {
        int2 e0 = sedge[i], e1 = sedge[i + 1];
        u16x4 b0 = x[(long)e0.x * 16 + q];
        u16x4 b1 = x[(long)e1.x * 16 + q];
        fma4(acc, __int_as_float(e0.y), bf4_to_f4(b0));
        fma4(acc, __int_as_float(e1.y), bf4_to_f4(b1));
        i += 2;
    }
    if (i < e) {
        int2 e0 = sedge[i];
        u16x4 b0 = x[(long)e0.x * 16 + q];
        fma4(acc, __int_as_float(e0.y), bf4_to_f4(b0));
    }
    __builtin_nontemporal_store(f4_to_bf4(acc), &y[(long)n * 16 + q]);
}

// Fused layer 3 + epilogue: y3 = spmm(Q_bf); v = (Tin + P + Q + y3)/4;
// out = v/max(||v||,eps) + Tin.  Gather from Q_bf (bf16); Tin f32; out f32.
// `out` may alias Tin (own-row) but NOT the P/Q buffers.
__global__ void spmm_final_kernel(const int* __restrict__ rowptr,
                                  const int2* __restrict__ sedge,
                                  const u16x4* __restrict__ Qb,   // gather + own-row
                                  const float4* __restrict__ Tin,
                                  const u16x4* __restrict__ Pb,   // own-row
                                  float* out) {
    int wid  = threadIdx.x >> 6;
    int lane = threadIdx.x & 63;
    int r = lane >> 4;
    int q = lane & 15;
    int n = (blockIdx.x * 4 + wid) * 4 + r;
    if (n >= N_NODES) return;
    int s = rowptr[n], e = rowptr[n + 1];
    float4 acc = make_float4(0.f, 0.f, 0.f, 0.f);
    int i = s;
    for (; i + 4 <= e; i += 4) {
        int2 e0 = sedge[i], e1 = sedge[i + 1], e2 = sedge[i + 2], e3 = sedge[i + 3];
        u16x4 b0 = Qb[(long)e0.x * 16 + q];
        u16x4 b1 = Qb[(long)e1.x * 16 + q];
        u16x4 b2 = Qb[(long)e2.x * 16 + q];
        u16x4 b3 = Qb[(long)e3.x * 16 + q];
        fma4(acc, __int_as_float(e0.y), bf4_to_f4(b0));
        fma4(acc, __int_as_float(e1.y), bf4_to_f4(b1));
        fma4(acc, __int_as_float(e2.y), bf4_to_f4(b2));
        fma4(acc, __int_as_float(e3.y), bf4_to_f4(b3));
    }
    if (i + 2 <= e) {
        int2 e0 = sedge[i], e1 = sedge[i + 1];
        u16x4 b0 = Qb[(long)e0.x * 16 + q];
        u16x4 b1 = Qb[(long)e1.x * 16 + q];
        fma4(acc, __int_as_float(e0.y), bf4_to_f4(b0));
        fma4(acc, __int_as_float(e1.y), bf4_to_f4(b1));
        i += 2;
    }
    if (i < e) {
        int2 e0 = sedge[i];
        u16x4 b0 = Qb[(long)e0.x * 16 + q];
        fma4(acc, __int_as_float(e0.y), bf4_to_f4(b0));
    }
    long o = (long)n * 16 + q;
    float4 t = Tin[o];
    float4 p = bf4_to_f4(Pb[o]);
    float4 qq = bf4_to_f4(Qb[o]);
    float4 v;
    v.x = (t.x + p.x + qq.x + acc.x) * 0.25f;
    v.y = (t.y + p.y + qq.y + acc.y) * 0.25f;
    v.z = (t.z + p.z + qq.z + acc.z) * 0.25f;
    v.w = (t.w + p.w + qq.w + acc.w) * 0.25f;
    float ss = v.x * v.x + v.y * v.y + v.z * v.z + v.w * v.w;
    #pragma unroll
    for (int off = 1; off < 16; off <<= 1) ss += __shfl_xor(ss, off, 64);
    float inv = 1.0f / fmaxf(sqrtf(ss), 1e-12f);
    f32x4 ov = { v.x * inv + t.x, v.y * inv + t.y, v.z * inv + t.z, v.w * inv + t.w };
    __builtin_nontemporal_store(ov, (f32x4*)&out[o * 4]);
}

extern "C" void kernel_launch(void* const* d_in, const int* in_sizes, int n_in,
                              void* d_out, int out_size, void* d_ws, size_t ws_size,
                              hipStream_t stream) {
    const float* user_emb = (const float*)d_in[0];
    const float* item_emb = (const float*)d_in[1];
    const int*   rows     = (const int*)d_in[2];
    const int*   cols     = (const int*)d_in[3];
    const float* weights  = (const float*)d_in[4];
    float* out = (float*)d_out;

    // Workspace (~83 MB): [A 51.2MB (tmpedge aliases first 28.8)][sedge][misc]
    float* A        = (float*)d_ws;
    int2*  tmpedge  = (int2*)d_ws;              // dead after bucket_sort
    int2*  sedge    = (int2*)(A + ND);          // E3 int2, final sorted
    int*   rowptr   = (int*)(sedge + E3);       // N3+1 (+pad)
    int*   bcnt     = rowptr + N3 + 2;          // NBUCKET
    int*   bbase    = bcnt + NBUCKET;           // NBUCKET+1
    int*   bcur     = bbase + NBUCKET + 1;      // NBUCKET

    float* o0 = out;
    float* o1 = out + ND;
    float* o2 = out + 2 * ND;
    float* T0 = o2;  // initial total lives in out[2] until b=0 consumes it

    const long v4_blocks  = (ND / 4 + 255) / 256;
    const long row_blocks = ((long)N_NODES + 15) / 16;

    // --- build all 3 CSRs via two-level bucket sort ---
    zero_bcnt_kernel<<<(NBUCKET + 255) / 256, 256, 0, stream>>>(bcnt);
    bucket_hist_kernel<<<NB_P1, 512, 0, stream>>>(rows, bcnt);
    bucket_scan_kernel<<<1, 1024, 0, stream>>>(bcnt, bbase, bcur, rowptr);
    bucket_scatter_kernel<<<NB_P1, 512, 0, stream>>>(rows, cols, weights, bcur, tmpedge);
    bucket_sort_kernel<<<NBUCKET, 256, 0, stream>>>(bbase, tmpedge, sedge, rowptr);

    concat_kernel<<<v4_blocks, 256, 0, stream>>>((const float4*)user_emb,
                                                 (const float4*)item_emb, (float4*)T0);

    // bf16 P/Q pairs live in dead buffers: b=0 -> o1, b=1 -> o2, b=2 -> ws A
    unsigned short* PQ[3] = { (unsigned short*)o1, (unsigned short*)o2,
                              (unsigned short*)A };
    float* Tins[3] = { T0, o0, o1 };
    float* Dsts[3] = { o0, o1, o2 };

    for (int b = 0; b < 3; ++b) {
        const int* rp = rowptr + (long)b * N_NODES;
        const float4* Tin = (const float4*)Tins[b];
        u16x4* Pb = (u16x4*)PQ[b];
        u16x4* Qb = (u16x4*)(PQ[b] + ND);
        float* Dst = Dsts[b];

        spmm_f32_bf16_kernel<<<row_blocks, 256, 0, stream>>>(rp, sedge, Tin, Pb);
        spmm_bf16_bf16_kernel<<<row_blocks, 256, 0, stream>>>(rp, sedge,
                                                              (const u16x4*)Pb, Qb);
        spmm_final_kernel<<<row_blocks, 256, 0, stream>>>(rp, sedge,
                                                          (const u16x4*)Qb, Tin,
                                                          (const u16x4*)Pb, Dst);
    }
}

// Round 8
// 466.644 us; speedup vs baseline: 5.6869x; 1.1812x over previous
//
#include <hip/hip_runtime.h>
#include <math.h>

#define N_USERS 100000
#define N_ITEMS 100000
#define EMB 64
#define N_NODES (N_USERS + N_ITEMS + 2)   // 200002
#define N_EDGES 1200000
#define E3 (3 * N_EDGES)                  // 3,600,000
#define N3 (3 * N_NODES)                  // 600,006
#define ND ((long)N_NODES * (long)EMB)    // 12,800,128

#define BUCKET_BITS 9
#define KPB 512                           // keys per bucket
#define NBUCKET ((N3 + KPB - 1) / KPB)    // 1172
#define CAP 3584                          // slots per bucket (mean 3072, +9 sigma)
#define EPB 4096                          // edges per scatter block
#define NB_P1 ((E3 + EPB - 1) / EPB)      // 879

typedef float f32x4 __attribute__((ext_vector_type(4)));
typedef float f32x8 __attribute__((ext_vector_type(8)));
typedef unsigned short u16x4 __attribute__((ext_vector_type(4)));
typedef unsigned short u16x8 __attribute__((ext_vector_type(8)));

__device__ inline unsigned short f2bf(float f) {   // RTNE
    unsigned int u = __float_as_uint(f);
    return (unsigned short)((u + 0x7FFFu + ((u >> 16) & 1u)) >> 16);
}

__device__ inline void fma8(f32x8& acc, float w, u16x8 s) {
    #pragma unroll
    for (int j = 0; j < 8; ++j)
        acc[j] = fmaf(w, __uint_as_float((unsigned int)s[j] << 16), acc[j]);
}
__device__ inline f32x8 bf8_to_f8(u16x8 s) {
    f32x8 f;
    #pragma unroll
    for (int j = 0; j < 8; ++j) f[j] = __uint_as_float((unsigned int)s[j] << 16);
    return f;
}
__device__ inline u16x8 f8_to_bf8(f32x8 f) {
    u16x8 s;
    #pragma unroll
    for (int j = 0; j < 8; ++j) s[j] = f2bf(f[j]);
    return s;
}

// total = concat(user,item) -> f32 T0 and bf16 Tb shadow
__global__ void concat_kernel(const float4* __restrict__ u,
                              const float4* __restrict__ it,
                              float4* __restrict__ t,
                              u16x4* __restrict__ tb) {
    long i = (long)blockIdx.x * blockDim.x + threadIdx.x;  // over ND/4
    if (i >= ND / 4) return;
    long n = i >> 4;
    float4 v = (n < (long)(N_USERS + 1)) ? u[i] : it[i - (long)(N_USERS + 1) * 16];
    t[i] = v;
    u16x4 b;
    b.x = f2bf(v.x); b.y = f2bf(v.y); b.z = f2bf(v.z); b.w = f2bf(v.w);
    tb[i] = b;
}

__global__ void init_bcur_kernel(int* __restrict__ bcur) {
    int i = blockIdx.x * blockDim.x + threadIdx.x;
    if (i < NBUCKET) bcur[i] = i * CAP;
}

// scatter into capacity-slotted buckets; per-block LDS aggregation
__global__ void bucket_scatter_kernel(const int* __restrict__ rows,
                                      const int* __restrict__ cols,
                                      const float* __restrict__ w,
                                      int* __restrict__ bcur,
                                      int2* __restrict__ tmpedge) {
    __shared__ int h[NBUCKET];
    __shared__ int lbase[NBUCKET];
    for (int i = threadIdx.x; i < NBUCKET; i += 512) h[i] = 0;
    __syncthreads();
    long base = (long)blockIdx.x * EPB;
    int keys[EPB / 512];
    for (int k = 0; k < EPB / 512; ++k) {
        long e = base + k * 512 + threadIdx.x;
        int key = -1;
        if (e < E3) {
            int b = (e >= 2L * N_EDGES) ? 2 : ((e >= N_EDGES) ? 1 : 0);
            key = b * N_NODES + rows[e];
            atomicAdd(&h[key >> BUCKET_BITS], 1);
        }
        keys[k] = key;
    }
    __syncthreads();
    for (int i = threadIdx.x; i < NBUCKET; i += 512) {
        int c = h[i];
        lbase[i] = c ? atomicAdd(&bcur[i], c) : 0;   // absolute slot (bcur pre-offset)
        h[i] = 0;
    }
    __syncthreads();
    for (int k = 0; k < EPB / 512; ++k) {
        long e = base + k * 512 + threadIdx.x;
        int key = keys[k];
        if (key >= 0) {
            int bk = key >> BUCKET_BITS;
            int pos = lbase[bk] + atomicAdd(&h[bk], 1);
            int2 pk;
            pk.x = ((key & (KPB - 1)) << 18) | cols[e];  // col < 2^18
            pk.y = __float_as_int(w[e]);
            tmpedge[pos] = pk;
        }
    }
}

// exclusive scan of bucket counts (derived from cursors); 1 block
__global__ void bucket_scan_kernel(const int* __restrict__ bcur, int* __restrict__ bbase,
                                   int* __restrict__ rowptr) {
    __shared__ int sm[1024];
    __shared__ int carry;
    int tid = threadIdx.x;
    if (tid == 0) carry = 0;
    __syncthreads();
    for (int base = 0; base < NBUCKET; base += 1024) {
        int i = base + tid;
        int v = (i < NBUCKET) ? (bcur[i] - i * CAP) : 0;
        sm[tid] = v;
        __syncthreads();
        for (int off = 1; off < 1024; off <<= 1) {
            int t = (tid >= off) ? sm[tid - off] : 0;
            __syncthreads();
            sm[tid] += t;
            __syncthreads();
        }
        if (i < NBUCKET) bbase[i] = sm[tid] - v + carry;
        __syncthreads();
        if (tid == 0) carry += sm[1023];
        __syncthreads();
    }
    if (tid == 0) { bbase[NBUCKET] = E3; rowptr[N3] = E3; }
}

// in-bucket counting sort + rowptr emission; one block per bucket
__global__ void bucket_sort_kernel(const int* __restrict__ bbase,
                                   const int2* __restrict__ tmpedge,
                                   int2* __restrict__ sedge,
                                   int* __restrict__ rowptr) {
    int g = blockIdx.x;
    int s = bbase[g];
    int cnt = bbase[g + 1] - s;
    long tb = (long)g * CAP;
    __shared__ int h[KPB];
    __shared__ int ex[KPB];
    __shared__ int tmp[256];
    int tid = threadIdx.x;
    h[tid * 2] = 0; h[tid * 2 + 1] = 0;
    __syncthreads();
    for (int i = tid; i < cnt; i += 256) atomicAdd(&h[tmpedge[tb + i].x >> 18], 1);
    __syncthreads();
    int a0 = h[tid * 2], a1 = h[tid * 2 + 1];
    int psum = a0 + a1;
    tmp[tid] = psum;
    __syncthreads();
    for (int off = 1; off < 256; off <<= 1) {
        int t = (tid >= off) ? tmp[tid - off] : 0;
        __syncthreads();
        tmp[tid] += t;
        __syncthreads();
    }
    int pex = tmp[tid] - psum;
    ex[tid * 2] = pex;
    ex[tid * 2 + 1] = pex + a0;
    __syncthreads();
    for (int j = tid; j < KPB; j += 256) {
        int key = g * KPB + j;
        if (key < N3) rowptr[key] = s + ex[j];
    }
    h[tid * 2] = ex[tid * 2];
    h[tid * 2 + 1] = ex[tid * 2 + 1];
    __syncthreads();
    for (int i = tid; i < cnt; i += 256) {
        int2 pk = tmpedge[tb + i];
        int kl = pk.x >> 18;
        int pos = s + atomicAdd(&h[kl], 1);
        int2 o;
        o.x = pk.x & 0x3FFFF;
        o.y = pk.y;
        sedge[pos] = o;
    }
}

// SpMM bf16->bf16: 8 lanes (u16x8 each) per row, 8 rows per wave.
__global__ void spmm_bf16_kernel(const int* __restrict__ rowptr,
                                 const int2* __restrict__ sedge,
                                 const u16x8* __restrict__ x,
                                 u16x8* __restrict__ y) {
    int wid  = threadIdx.x >> 6;
    int lane = threadIdx.x & 63;
    int r = lane >> 3;
    int q = lane & 7;
    int n = (blockIdx.x * 4 + wid) * 8 + r;
    if (n >= N_NODES) return;
    int s = rowptr[n], e = rowptr[n + 1];
    f32x8 acc = {0.f, 0.f, 0.f, 0.f, 0.f, 0.f, 0.f, 0.f};
    int i = s;
    for (; i + 4 <= e; i += 4) {
        int2 e0 = sedge[i], e1 = sedge[i + 1], e2 = sedge[i + 2], e3 = sedge[i + 3];
        u16x8 b0 = x[(long)e0.x * 8 + q];
        u16x8 b1 = x[(long)e1.x * 8 + q];
        u16x8 b2 = x[(long)e2.x * 8 + q];
        u16x8 b3 = x[(long)e3.x * 8 + q];
        fma8(acc, __int_as_float(e0.y), b0);
        fma8(acc, __int_as_float(e1.y), b1);
        fma8(acc, __int_as_float(e2.y), b2);
        fma8(acc, __int_as_float(e3.y), b3);
    }
    if (i + 2 <= e) {
        int2 e0 = sedge[i], e1 = sedge[i + 1];
        u16x8 b0 = x[(long)e0.x * 8 + q];
        u16x8 b1 = x[(long)e1.x * 8 + q];
        fma8(acc, __int_as_float(e0.y), b0);
        fma8(acc, __int_as_float(e1.y), b1);
        i += 2;
    }
    if (i < e) {
        int2 e0 = sedge[i];
        u16x8 b0 = x[(long)e0.x * 8 + q];
        fma8(acc, __int_as_float(e0.y), b0);
    }
    __builtin_nontemporal_store(f8_to_bf8(acc), &y[(long)n * 8 + q]);
}

// Fused layer 3 + epilogue: y3 = spmm(Qb); v = (Tin + P + Q + y3)/4;
// out = v/max(||v||,eps) + Tin; also emits bf16 shadow of out (next Tin) if TbOut.
__global__ void spmm_final_kernel(const int* __restrict__ rowptr,
                                  const int2* __restrict__ sedge,
                                  const u16x8* __restrict__ Qb,
                                  const float* __restrict__ Tin,
                                  const u16x8* __restrict__ Pb,
                                  float* __restrict__ outp,
                                  u16x8* __restrict__ TbOut) {
    int wid  = threadIdx.x >> 6;
    int lane = threadIdx.x & 63;
    int r = lane >> 3;
    int q = lane & 7;
    int n = (blockIdx.x * 4 + wid) * 8 + r;
    if (n >= N_NODES) return;
    int s = rowptr[n], e = rowptr[n + 1];
    f32x8 acc = {0.f, 0.f, 0.f, 0.f, 0.f, 0.f, 0.f, 0.f};
    int i = s;
    for (; i + 4 <= e; i += 4) {
        int2 e0 = sedge[i], e1 = sedge[i + 1], e2 = sedge[i + 2], e3 = sedge[i + 3];
        u16x8 b0 = Qb[(long)e0.x * 8 + q];
        u16x8 b1 = Qb[(long)e1.x * 8 + q];
        u16x8 b2 = Qb[(long)e2.x * 8 + q];
        u16x8 b3 = Qb[(long)e3.x * 8 + q];
        fma8(acc, __int_as_float(e0.y), b0);
        fma8(acc, __int_as_float(e1.y), b1);
        fma8(acc, __int_as_float(e2.y), b2);
        fma8(acc, __int_as_float(e3.y), b3);
    }
    if (i + 2 <= e) {
        int2 e0 = sedge[i], e1 = sedge[i + 1];
        u16x8 b0 = Qb[(long)e0.x * 8 + q];
        u16x8 b1 = Qb[(long)e1.x * 8 + q];
        fma8(acc, __int_as_float(e0.y), b0);
        fma8(acc, __int_as_float(e1.y), b1);
        i += 2;
    }
    if (i < e) {
        int2 e0 = sedge[i];
        u16x8 b0 = Qb[(long)e0.x * 8 + q];
        fma8(acc, __int_as_float(e0.y), b0);
    }
    long o = (long)n * 8 + q;
    f32x8 t = *(const f32x8*)(Tin + (long)n * EMB + q * 8);
    f32x8 p = bf8_to_f8(Pb[o]);
    f32x8 qv = bf8_to_f8(Qb[o]);
    f32x8 v;
    float ss = 0.f;
    #pragma unroll
    for (int j = 0; j < 8; ++j) {
        v[j] = (t[j] + p[j] + qv[j] + acc[j]) * 0.25f;
        ss = fmaf(v[j], v[j], ss);
    }
    ss += __shfl_xor(ss, 1, 64);
    ss += __shfl_xor(ss, 2, 64);
    ss += __shfl_xor(ss, 4, 64);
    float inv = 1.0f / fmaxf(sqrtf(ss), 1e-12f);
    f32x8 ov;
    #pragma unroll
    for (int j = 0; j < 8; ++j) ov[j] = fmaf(v[j], inv, t[j]);
    __builtin_nontemporal_store(ov, (f32x8*)(outp + (long)n * EMB + q * 8));
    if (TbOut) __builtin_nontemporal_store(f8_to_bf8(ov), &TbOut[o]);
}

extern "C" void kernel_launch(void* const* d_in, const int* in_sizes, int n_in,
                              void* d_out, int out_size, void* d_ws, size_t ws_size,
                              hipStream_t stream) {
    const float* user_emb = (const float*)d_in[0];
    const float* item_emb = (const float*)d_in[1];
    const int*   rows     = (const int*)d_in[2];
    const int*   cols     = (const int*)d_in[3];
    const float* weights  = (const float*)d_in[4];
    float* out = (float*)d_out;

    // Workspace (~142 MB of ~614 MB)
    unsigned short* Tb   = (unsigned short*)d_ws;        // ND u16 (25.6 MB)
    unsigned short* Pq   = Tb + ND;                      // Pb: ND u16
    unsigned short* Qq   = Pq + ND;                      // Qb: ND u16
    int2* tmpedge = (int2*)(Qq + ND);                    // NBUCKET*CAP int2 (33.6 MB)
    int2* sedge   = tmpedge + (long)NBUCKET * CAP;       // E3 int2 (28.8 MB)
    int*  rowptr  = (int*)(sedge + E3);                  // N3+1 (+pad)
    int*  bbase   = rowptr + N3 + 2;                     // NBUCKET+1
    int*  bcur    = bbase + NBUCKET + 2;                 // NBUCKET

    float* o0 = out;
    float* o1 = out + ND;
    float* o2 = out + 2 * ND;
    float* T0 = o2;  // f32 total lives in out[2] until b=2 overwrites it

    const long v4_blocks  = (ND / 4 + 255) / 256;
    const long row_blocks = ((long)N_NODES + 31) / 32;   // 32 rows/block

    // --- build all 3 CSRs: capacity-slotted bucket sort (no pre-histogram) ---
    init_bcur_kernel<<<(NBUCKET + 255) / 256, 256, 0, stream>>>(bcur);
    bucket_scatter_kernel<<<NB_P1, 512, 0, stream>>>(rows, cols, weights, bcur, tmpedge);
    bucket_scan_kernel<<<1, 1024, 0, stream>>>(bcur, bbase, rowptr);
    bucket_sort_kernel<<<NBUCKET, 256, 0, stream>>>(bbase, tmpedge, sedge, rowptr);

    concat_kernel<<<v4_blocks, 256, 0, stream>>>((const float4*)user_emb,
                                                 (const float4*)item_emb,
                                                 (float4*)T0, (u16x4*)Tb);

    float* Tins[3] = { T0, o0, o1 };
    float* Dsts[3] = { o0, o1, o2 };

    for (int b = 0; b < 3; ++b) {
        const int* rp = rowptr + (long)b * N_NODES;
        u16x8* Pb = (u16x8*)Pq;
        u16x8* Qb = (u16x8*)Qq;

        spmm_bf16_kernel<<<row_blocks, 256, 0, stream>>>(rp, sedge, (const u16x8*)Tb, Pb);
        spmm_bf16_kernel<<<row_blocks, 256, 0, stream>>>(rp, sedge, (const u16x8*)Pb, Qb);
        spmm_final_kernel<<<row_blocks, 256, 0, stream>>>(rp, sedge, (const u16x8*)Qb,
                                                          Tins[b], (const u16x8*)Pb,
                                                          Dsts[b],
                                                          (b < 2) ? (u16x8*)Tb : nullptr);
    }
}